// Round 12
// baseline (295.466 us; speedup 1.0000x reference)
//
#include <hip/hip_runtime.h>
#include <cstdint>
#include <cstddef>

#define IN_F 4096
#define OUT_F 11008
#define M_ROWS 4096
#define QZ_STRIDE (OUT_F / 8) /* 1376 */
#define NKT (IN_F / 128)      /* 32 K-tiles of 128 */
#define NGROUPS 32
#define KC (IN_F / 64) /* 64 1KB chunks per 16-row tile */

typedef __attribute__((ext_vector_type(4))) float f32x4;
typedef __attribute__((ext_vector_type(4))) int i32x4;
typedef __attribute__((ext_vector_type(8))) __bf16 bf16x8;
typedef uint32_t u32;
typedef uint16_t u16;
typedef uint8_t u8;

__device__ __forceinline__ u16 f2bf(float f) {
  u32 u = __builtin_bit_cast(u32, f);
  u += 0x7FFFu + ((u >> 16) & 1u);
  return (u16)(u >> 16);
}

// ---- x fp32 -> int8 per-row scaled, FRAGMENT-MAJOR blobs; xs[row] = rowmax/127 ----
// Blob layout: tile (r16 = row>>4, c = k>>6) is 1KB: byte[(row&15 | ((k>>4)&3)<<4)*16 + (k&15)]
__global__ __launch_bounds__(256) void conv_x_i8(const float* __restrict__ x,
                                                 u8* __restrict__ xqf,
                                                 float* __restrict__ xs) {
  const int row = blockIdx.x;
  const int tid = threadIdx.x;
  const float* xr = x + (size_t)row * IN_F;
  float4 v[4];
#pragma unroll
  for (int j = 0; j < 4; ++j)
    v[j] = reinterpret_cast<const float4*>(xr)[tid * 4 + j];
  float am = 0.f;
#pragma unroll
  for (int j = 0; j < 4; ++j)
    am = fmaxf(am, fmaxf(fmaxf(fabsf(v[j].x), fabsf(v[j].y)),
                         fmaxf(fabsf(v[j].z), fabsf(v[j].w))));
#pragma unroll
  for (int off = 32; off > 0; off >>= 1) am = fmaxf(am, __shfl_xor(am, off, 64));
  __shared__ float wmax[4];
  if ((tid & 63) == 0) wmax[tid >> 6] = am;
  __syncthreads();
  am = fmaxf(fmaxf(wmax[0], wmax[1]), fmaxf(wmax[2], wmax[3]));
  const float amc = fmaxf(am, 1e-30f);
  const float inv = 127.f / amc;
  if (tid == 0) xs[row] = amc / 127.f;
  u32 o[4];
#pragma unroll
  for (int j = 0; j < 4; ++j) {
    u32 b0 = (u32)(u8)(int8_t)__float2int_rn(v[j].x * inv);
    u32 b1 = (u32)(u8)(int8_t)__float2int_rn(v[j].y * inv);
    u32 b2 = (u32)(u8)(int8_t)__float2int_rn(v[j].z * inv);
    u32 b3 = (u32)(u8)(int8_t)__float2int_rn(v[j].w * inv);
    o[j] = b0 | (b1 << 8) | (b2 << 16) | (b3 << 24);
  }
  const int k0 = tid * 16;
  u8* dst = xqf + ((size_t)(row >> 4) * KC + (k0 >> 6)) * 1024 +
            (size_t)(((row & 15) + (((k0 >> 4) & 3) << 4)) * 16);
  *reinterpret_cast<uint4*>(dst) = make_uint4(o[0], o[1], o[2], o[3]);
}

// ------- per-column W scale: S_col = 15 * max_g s[g][col] / 127 -------
__global__ void colscale_kernel(const float* __restrict__ scl,
                                float* __restrict__ Scol,
                                float* __restrict__ invScol) {
  const int n = blockIdx.x * 256 + threadIdx.x;
  if (n >= OUT_F) return;
  float m = 0.f;
#pragma unroll 4
  for (int g = 0; g < NGROUPS; ++g) m = fmaxf(m, scl[(size_t)g * OUT_F + n]);
  const float S = m * (15.f / 127.f);
  Scol[n] = S;
  invScol[n] = 1.f / S;
}

// ------- dequant qweight -> fragment-major int8 blobs = round((w4-z)*s/S_col) -------
__global__ void dequant_i8(const int* __restrict__ qw, const int* __restrict__ qz,
                           const float* __restrict__ scl,
                           const float* __restrict__ invScol,
                           u8* __restrict__ wqf) {
  const int nl = threadIdx.x & 31, rl = threadIdx.x >> 5;
  const int n = blockIdx.x * 32 + nl;
  const int r = blockIdx.y * 8 + rl; // qweight row -> k = 8r..8r+7
  const int g = r >> 4;              // k/128
  u32 q = (u32)qw[(size_t)r * OUT_F + n];
  const int z = (int)(((u32)qz[g * QZ_STRIDE + (n >> 3)] >> (4 * (n & 7))) & 15u);
  const float si = scl[(size_t)g * OUT_F + n] * invScol[n];
  u32 lo = 0, hi = 0;
#pragma unroll
  for (int e = 0; e < 4; ++e) {
    float f = fminf(fmaxf((float)((int)((q >> (4 * e)) & 15u) - z) * si, -127.f), 127.f);
    lo |= ((u32)(u8)(int8_t)__float2int_rn(f)) << (8 * e);
  }
#pragma unroll
  for (int e = 0; e < 4; ++e) {
    float f = fminf(fmaxf((float)((int)((q >> (16 + 4 * e)) & 15u) - z) * si, -127.f), 127.f);
    hi |= ((u32)(u8)(int8_t)__float2int_rn(f)) << (8 * e);
  }
  const int k0 = r * 8;
  u8* dst = wqf + ((size_t)(n >> 4) * KC + (k0 >> 6)) * 1024 +
            (size_t)(((n & 15) + (((k0 >> 4) & 3) << 4)) * 16) + (k0 & 8);
  *reinterpret_cast<uint2*>(dst) = make_uint2(lo, hi);
}

// =======================================================================
// INT8 GEMM, register-direct (no LDS, no barriers): block 256x128, 8 fully
// independent waves (4M x 2N), wave tile 64x64, acc 4x4 i32x4 (AGPRs).
// Fragments load straight from fragment-major blobs: one global_load_dwordx4
// per (tile,chunk) = contiguous 1KB per wave, perfectly coalesced.
// Software pipeline per wave (compiler emits counted vmcnt, never 0):
//   LOADT(bank1,u+1); MFMA(bank0); LOADT(bank0,u+2); MFMA(bank1)
// Waves drift freely; MFMA/VMEM/VALU overlap across waves (no lockstep).
// =======================================================================
__global__ __launch_bounds__(512, 2) void gemm_reg_i8(
    const u8* __restrict__ xqf, const u8* __restrict__ wqf,
    const float* __restrict__ Scol, const float* __restrict__ xs,
    const float* __restrict__ bias, float* __restrict__ out) {
  const int tid = threadIdx.x;
  const int lane = tid & 63, wid = tid >> 6;
  // bijective XCD swizzle: gridDim.x = 1376, 1376 % 8 == 0
  const int cpx = (int)gridDim.x >> 3;
  const int swz = ((int)blockIdx.x & 7) * cpx + ((int)blockIdx.x >> 3);
  const int mIdx = swz & 15, nIdx = swz >> 4; // 16 x 86
  const int m0 = mIdx * 256, n0 = nIdx * 128;
  const int wr = wid >> 1, wc = wid & 1;

  const u8* pa[4];
  const u8* pb[4];
#pragma unroll
  for (int mi = 0; mi < 4; ++mi)
    pa[mi] = xqf + ((size_t)((m0 >> 4) + wr * 4 + mi) * KC) * 1024 + lane * 16;
#pragma unroll
  for (int ni = 0; ni < 4; ++ni)
    pb[ni] = wqf + ((size_t)((n0 >> 4) + wc * 4 + ni) * KC) * 1024 + lane * 16;

  i32x4 a0[4][2], b0[4][2], a1[4][2], b1[4][2];
  i32x4 acc[4][4] = {};

#define LOADT(A, B, u)                                                        \
  do {                                                                        \
    const int _off = (u) * 2048;                                              \
    _Pragma("unroll") for (int mi = 0; mi < 4; ++mi) {                        \
      A[mi][0] = *reinterpret_cast<const i32x4*>(pa[mi] + _off);              \
      A[mi][1] = *reinterpret_cast<const i32x4*>(pa[mi] + _off + 1024);       \
    }                                                                         \
    _Pragma("unroll") for (int ni = 0; ni < 4; ++ni) {                        \
      B[ni][0] = *reinterpret_cast<const i32x4*>(pb[ni] + _off);              \
      B[ni][1] = *reinterpret_cast<const i32x4*>(pb[ni] + _off + 1024);       \
    }                                                                         \
  } while (0)

#define MFMAT(A, B)                                                           \
  do {                                                                        \
    __builtin_amdgcn_s_setprio(1);                                            \
    _Pragma("unroll") for (int mi = 0; mi < 4; ++mi)                          \
        _Pragma("unroll") for (int ni = 0; ni < 4; ++ni) {                    \
      acc[mi][ni] = __builtin_amdgcn_mfma_i32_16x16x64_i8(                    \
          A[mi][0], B[ni][0], acc[mi][ni], 0, 0, 0);                          \
      acc[mi][ni] = __builtin_amdgcn_mfma_i32_16x16x64_i8(                    \
          A[mi][1], B[ni][1], acc[mi][ni], 0, 0, 0);                          \
    }                                                                         \
    __builtin_amdgcn_s_setprio(0);                                            \
  } while (0)

  LOADT(a0, b0, 0);
  for (int u = 0; u < NKT; u += 2) {
    if (u + 1 < NKT) LOADT(a1, b1, u + 1);
    MFMAT(a0, b0);
    if (u + 2 < NKT) LOADT(a0, b0, u + 2);
    if (u + 1 < NKT) MFMAT(a1, b1);
  }

  // ---- epilogue: out = xs[row]*Scol[col]*(float)acc + bias ----
  const int crow = (lane >> 4) * 4, ccol = lane & 15;
#pragma unroll
  for (int mi = 0; mi < 4; ++mi) {
    const int rowb = m0 + wr * 64 + mi * 16 + crow;
    float sxv[4];
#pragma unroll
    for (int r2 = 0; r2 < 4; ++r2) sxv[r2] = xs[rowb + r2];
#pragma unroll
    for (int ni = 0; ni < 4; ++ni) {
      const int col = n0 + wc * 64 + ni * 16 + ccol;
      const float bv = bias[col];
      const float sv = Scol[col];
#pragma unroll
      for (int r2 = 0; r2 < 4; ++r2)
        __builtin_nontemporal_store(
            fmaf(sxv[r2] * sv, (float)acc[mi][ni][r2], bv),
            out + (size_t)(rowb + r2) * OUT_F + col);
    }
  }
}

// ---------------- fused fallback (ws too small): bf16 128^2 kernel ----------------
__global__ __launch_bounds__(256, 2) void gemm_fused(
    const float* __restrict__ x, const int* __restrict__ qw,
    const int* __restrict__ qz, const float* __restrict__ sc,
    const float* __restrict__ bias, float* __restrict__ out) {
  __shared__ u16 Asb[128 * 64];
  __shared__ u16 Bsb[128 * 64];
  const int tid = threadIdx.x;
  const int lane = tid & 63, wid = tid >> 6;
  const int bm = blockIdx.x & 31, bn = blockIdx.x >> 5;
  const int m0 = bm * 128, n0 = bn * 128;
  const int wr = wid >> 1, wc = wid & 1;
  const int frow = lane & 15, fk = (lane >> 4) * 8;
  f32x4 acc[4][4] = {};

  for (int kt = 0; kt < 64; ++kt) {
    const int k0 = kt * 64;
#pragma unroll
    for (int it = 0; it < 8; ++it) {
      int c = it * 256 + tid;
      int row = c >> 4, c4 = c & 15;
      float4 v = *reinterpret_cast<const float4*>(
          x + (size_t)(m0 + row) * IN_F + k0 + c4 * 4);
      uint2 o;
      o.x = (u32)f2bf(v.x) | ((u32)f2bf(v.y) << 16);
      o.y = (u32)f2bf(v.z) | ((u32)f2bf(v.w) << 16);
      *reinterpret_cast<uint2*>(Asb + row * 64 + c4 * 4) = o;
    }
    {
      int nl = tid & 127, rq = tid >> 7;
      int n = n0 + nl;
      int gq = k0 >> 7;
      int z = (int)(((u32)qz[gq * QZ_STRIDE + (n >> 3)] >> (4 * (n & 7))) & 15u);
      float s = sc[gq * OUT_F + n];
#pragma unroll
      for (int j = 0; j < 4; ++j) {
        int r = (k0 >> 3) + rq * 4 + j;
        u32 q = (u32)qw[(size_t)r * OUT_F + n];
        u32 o[4];
#pragma unroll
        for (int e = 0; e < 4; ++e) {
          u16 lo = f2bf(s * (float)((int)((q >> (8 * e)) & 15u) - z));
          u16 hi = f2bf(s * (float)((int)((q >> (8 * e + 4)) & 15u) - z));
          o[e] = (u32)lo | ((u32)hi << 16);
        }
        *reinterpret_cast<uint4*>(Bsb + nl * 64 + (rq * 4 + j) * 8) =
            make_uint4(o[0], o[1], o[2], o[3]);
      }
    }
    __syncthreads();
#pragma unroll
    for (int kk = 0; kk < 64; kk += 32) {
      bf16x8 a[4], b[4];
#pragma unroll
      for (int mi = 0; mi < 4; ++mi)
        a[mi] = *reinterpret_cast<const bf16x8*>(Asb + (wr * 64 + mi * 16 + frow) * 64 + kk + fk);
#pragma unroll
      for (int ni = 0; ni < 4; ++ni)
        b[ni] = *reinterpret_cast<const bf16x8*>(Bsb + (wc * 64 + ni * 16 + frow) * 64 + kk + fk);
#pragma unroll
      for (int mi = 0; mi < 4; ++mi)
#pragma unroll
        for (int ni = 0; ni < 4; ++ni)
          acc[mi][ni] = __builtin_amdgcn_mfma_f32_16x16x32_bf16(a[mi], b[ni], acc[mi][ni], 0, 0, 0);
    }
    __syncthreads();
  }
  const int crow = (lane >> 4) * 4, ccol = lane & 15;
#pragma unroll
  for (int mi = 0; mi < 4; ++mi) {
#pragma unroll
    for (int ni = 0; ni < 4; ++ni) {
      int col = n0 + wc * 64 + ni * 16 + ccol;
      float bv = bias[col];
      int rowb = m0 + wr * 64 + mi * 16 + crow;
#pragma unroll
      for (int r2 = 0; r2 < 4; ++r2)
        out[(size_t)(rowb + r2) * OUT_F + col] = acc[mi][ni][r2] + bv;
    }
  }
}

extern "C" void kernel_launch(void* const* d_in, const int* in_sizes, int n_in,
                              void* d_out, int out_size, void* d_ws, size_t ws_size,
                              hipStream_t stream) {
  const float* x = (const float*)d_in[0];
  const int* qw = (const int*)d_in[1];
  const float* sc = (const float*)d_in[2];
  const int* qz = (const int*)d_in[3];
  const float* bias = (const float*)d_in[4];
  float* out = (float*)d_out;

  const size_t xq_bytes = (size_t)M_ROWS * IN_F;  // 16 MiB
  const size_t wq_bytes = (size_t)OUT_F * IN_F;   // ~43 MiB
  const size_t xs_bytes = (size_t)M_ROWS * 4;     // 16 KiB
  const size_t sc_bytes = (size_t)OUT_F * 4;      // 43 KiB each

  if (ws_size >= xq_bytes + wq_bytes + xs_bytes + 2 * sc_bytes) {
    u8* xqp = (u8*)d_ws;
    u8* wqp = (u8*)d_ws + xq_bytes;
    float* xsp = (float*)((u8*)d_ws + xq_bytes + wq_bytes);
    float* Scolp = (float*)((u8*)d_ws + xq_bytes + wq_bytes + xs_bytes);
    float* invScolp = Scolp + OUT_F;
    hipLaunchKernelGGL(conv_x_i8, dim3(M_ROWS), dim3(256), 0, stream, x, xqp, xsp);
    hipLaunchKernelGGL(colscale_kernel, dim3((OUT_F + 255) / 256), dim3(256), 0,
                       stream, sc, Scolp, invScolp);
    hipLaunchKernelGGL(dequant_i8, dim3(OUT_F / 32, 512 / 8), dim3(256), 0,
                       stream, qw, qz, sc, invScolp, wqp);
    hipLaunchKernelGGL(gemm_reg_i8, dim3((M_ROWS / 256) * (OUT_F / 128)),
                       dim3(512), 0, stream, xqp, wqp, Scolp, xsp, bias, out);
  } else {
    hipLaunchKernelGGL(gemm_fused, dim3(32 * 86), dim3(256), 0, stream, x, qw,
                       qz, sc, bias, out);
  }
}

// Round 15
// 212.536 us; speedup vs baseline: 1.3902x; 1.3902x over previous
//
#include <hip/hip_runtime.h>
#include <cstdint>
#include <cstddef>

#define IN_F 4096
#define OUT_F 11008
#define M_ROWS 4096
#define QZ_STRIDE (OUT_F / 8) /* 1376 */
#define NKT (IN_F / 128)      /* 32 K-tiles of 128 */
#define NGROUPS 32

typedef __attribute__((ext_vector_type(4))) float f32x4;
typedef __attribute__((ext_vector_type(4))) int i32x4;
typedef __attribute__((ext_vector_type(8))) __bf16 bf16x8;
typedef uint32_t u32;
typedef uint16_t u16;
typedef uint8_t u8;

__device__ __forceinline__ u16 f2bf(float f) {
  u32 u = __builtin_bit_cast(u32, f);
  u += 0x7FFFu + ((u >> 16) & 1u);
  return (u16)(u >> 16);
}

// ---------------- x fp32 -> int8 per-row scaled; xs[row] = rowmax/127 ----------------
__global__ __launch_bounds__(256) void conv_x_i8(const float* __restrict__ x,
                                                 u8* __restrict__ xq,
                                                 float* __restrict__ xs) {
  const int row = blockIdx.x;
  const int tid = threadIdx.x;
  const float* xr = x + (size_t)row * IN_F;
  float4 v[4];
#pragma unroll
  for (int j = 0; j < 4; ++j)
    v[j] = reinterpret_cast<const float4*>(xr)[tid * 4 + j];
  float am = 0.f;
#pragma unroll
  for (int j = 0; j < 4; ++j)
    am = fmaxf(am, fmaxf(fmaxf(fabsf(v[j].x), fabsf(v[j].y)),
                         fmaxf(fabsf(v[j].z), fabsf(v[j].w))));
#pragma unroll
  for (int off = 32; off > 0; off >>= 1) am = fmaxf(am, __shfl_xor(am, off, 64));
  __shared__ float wmax[4];
  if ((tid & 63) == 0) wmax[tid >> 6] = am;
  __syncthreads();
  am = fmaxf(fmaxf(wmax[0], wmax[1]), fmaxf(wmax[2], wmax[3]));
  const float amc = fmaxf(am, 1e-30f);
  const float inv = 127.f / amc;
  if (tid == 0) xs[row] = amc / 127.f;
  u32 o[4];
#pragma unroll
  for (int j = 0; j < 4; ++j) {
    u32 b0 = (u32)(u8)(int8_t)__float2int_rn(v[j].x * inv);
    u32 b1 = (u32)(u8)(int8_t)__float2int_rn(v[j].y * inv);
    u32 b2 = (u32)(u8)(int8_t)__float2int_rn(v[j].z * inv);
    u32 b3 = (u32)(u8)(int8_t)__float2int_rn(v[j].w * inv);
    o[j] = b0 | (b1 << 8) | (b2 << 16) | (b3 << 24);
  }
  *reinterpret_cast<uint4*>(xq + (size_t)row * IN_F + tid * 16) =
      make_uint4(o[0], o[1], o[2], o[3]);
}

// ------- per-column W scale: S_col = 15 * max_g s[g][col] / 127 -------
__global__ void colscale_kernel(const float* __restrict__ scl,
                                float* __restrict__ Scol,
                                float* __restrict__ invScol) {
  const int n = blockIdx.x * 256 + threadIdx.x;
  if (n >= OUT_F) return;
  float m = 0.f;
#pragma unroll 4
  for (int g = 0; g < NGROUPS; ++g) m = fmaxf(m, scl[(size_t)g * OUT_F + n]);
  const float S = m * (15.f / 127.f);
  Scol[n] = S;
  invScol[n] = 1.f / S;
}

// ------- dequant qweight -> WQ [OUT_F][IN_F] int8 = round((w4-z)*s/S_col) -------
__global__ void dequant_i8(const int* __restrict__ qw, const int* __restrict__ qz,
                           const float* __restrict__ scl,
                           const float* __restrict__ invScol,
                           u8* __restrict__ wq8) {
  const int nl = threadIdx.x & 31, rl = threadIdx.x >> 5;
  const int n = blockIdx.x * 32 + nl;
  const int r = blockIdx.y * 8 + rl; // qweight row -> k = 8r..8r+7
  const int g = r >> 4;              // k/128
  u32 q = (u32)qw[(size_t)r * OUT_F + n];
  const int z = (int)(((u32)qz[g * QZ_STRIDE + (n >> 3)] >> (4 * (n & 7))) & 15u);
  const float si = scl[(size_t)g * OUT_F + n] * invScol[n];
  u32 lo = 0, hi = 0;
#pragma unroll
  for (int e = 0; e < 4; ++e) {
    float f = fminf(fmaxf((float)((int)((q >> (4 * e)) & 15u) - z) * si, -127.f), 127.f);
    lo |= ((u32)(u8)(int8_t)__float2int_rn(f)) << (8 * e);
  }
#pragma unroll
  for (int e = 0; e < 4; ++e) {
    float f = fminf(fmaxf((float)((int)((q >> (16 + 4 * e)) & 15u) - z) * si, -127.f), 127.f);
    hi |= ((u32)(u8)(int8_t)__float2int_rn(f)) << (8 * e);
  }
  *reinterpret_cast<uint2*>(wq8 + (size_t)n * IN_F + r * 8) = make_uint2(lo, hi);
}

// =======================================================================
// INT8 GEMM: 256x256 tile, BK=128, 8 waves (2M x 4N), pure i32 MFMA chain.
// R10's 2-region m201-ordered schedule (best measured) + two memory fixes:
//  (1) XCD-rectangle block mapping: xcd owns m-pair {2*xcd, 2*xcd+1} x all n
//      -> per-XCD A working set = 2MB (L2-resident), B streams via L3.
//  (2) Epilogue stages C through LDS (two 128-row passes); store pass:
//      wave w owns rows w*16+rr, lane reads cs[r*256 + lane*4] (b128,
//      conflict-free) -> 1024B-contiguous NT stores per wave per row.
// LDS buffers addressed by runtime arithmetic (no pointer array: gfx950
// rejects LDS addrspacecast in static initializers).
// =======================================================================
#define ASB(i) (SMEM + ((i) << 15))
#define BSB(i) (SMEM + 65536 + ((i) << 15))

__global__ __launch_bounds__(512, 2) void gemm256_i8(
    const u8* __restrict__ xq, const u8* __restrict__ wq,
    const float* __restrict__ Scol, const float* __restrict__ xs,
    const float* __restrict__ bias, float* __restrict__ out) {
  __shared__ __align__(16) u8 SMEM[131072];
  const int tid = threadIdx.x;
  const int lane = tid & 63, wid = tid >> 6;
  // XCD-rectangle mapping: gridDim.x = 688 = 8 XCDs x 86
  const int xcd = (int)blockIdx.x & 7;
  const int l = (int)blockIdx.x >> 3; // 0..85
  const int mIdx = xcd * 2 + (l & 1); // 0..15
  const int nIdx = l >> 1;            // 0..42
  const int m0 = mIdx * 256, n0 = nIdx * 256;
  const int wr = wid >> 2, wc = wid & 3;
  const int frow = lane & 15, q4 = lane >> 4, f7 = lane & 7;
  const int lrow = lane >> 3, ls = lane & 7;

  // swizzled ds_read byte offsets: 16B slot (q4 | 4|q4) ^ (row&7)
  const int colb0 = ((q4 ^ f7) << 4);
  const int colb1 = (((4 | q4) ^ f7) << 4);
  const int arowB = (wr * 128 + frow) * 128; // byte base; mi stride 16*128=2048
  const int browB = (wc * 64 + frow) * 128;  // ni stride 2048

  // staging: per-lane global base (row = +lrow, 16B slot inverse-swizzled)
  const u8* gA = xq + (size_t)(m0 + lrow) * IN_F + ((ls ^ lrow) << 4);
  const u8* gB = wq + (size_t)(n0 + lrow) * IN_F + ((ls ^ lrow) << 4);
  const int rsbase = (wid >> 2) * 128 + (wid & 3) * 16; // + j*8 + h*64

  i32x4 acc[8][4] = {};
  i32x4 af[4][2], ah[4][2], bf[4][2];

  auto stage = [&](u8* ldsb, const u8* gl, int u, int h) {
#pragma unroll
    for (int j = 0; j < 2; ++j) {
      const int rowstart = rsbase + j * 8 + h * 64;
      __builtin_amdgcn_global_load_lds(
          (__attribute__((address_space(1))) void*)(gl + (size_t)rowstart * IN_F + (size_t)u * 128),
          (__attribute__((address_space(3))) void*)(ldsb + rowstart * 128), 16, 0, 0);
    }
  };

  // ---- prologue: full tiles 0,1 (16 loads); wait tile 0; read lo frags ----
  stage(BSB(0), gB, 0, 0);
  stage(BSB(0), gB, 0, 1);
  stage(ASB(0), gA, 0, 0);
  stage(ASB(0), gA, 0, 1);
  stage(BSB(1), gB, 1, 0);
  stage(BSB(1), gB, 1, 1);
  stage(ASB(1), gA, 1, 0);
  stage(ASB(1), gA, 1, 1);
  asm volatile("s_waitcnt vmcnt(8)" ::: "memory");
  __builtin_amdgcn_s_barrier();
  {
    const u8* Ac = ASB(0);
    const u8* Bc = BSB(0);
#pragma unroll
    for (int ni = 0; ni < 4; ++ni) {
      bf[ni][0] = *reinterpret_cast<const i32x4*>(Bc + browB + ni * 2048 + colb0);
      bf[ni][1] = *reinterpret_cast<const i32x4*>(Bc + browB + ni * 2048 + colb1);
    }
#pragma unroll
    for (int mi = 0; mi < 4; ++mi) {
      af[mi][0] = *reinterpret_cast<const i32x4*>(Ac + arowB + mi * 2048 + colb0);
      af[mi][1] = *reinterpret_cast<const i32x4*>(Ac + arowB + mi * 2048 + colb1);
    }
  }

  for (int u = 0; u < NKT; ++u) {
    const int cur = u & 1;
    const u8* Ac = ASB(cur);
    const u8* An = ASB(cur ^ 1);
    const u8* Bn = BSB(cur ^ 1);
    const bool stT = (u + 2 < NKT);

    // ---- R1: [bar; lgkm0; MFMA lo] ; stage B(u+2); read ah(u) ----
    __builtin_amdgcn_s_barrier();
    asm volatile("s_waitcnt lgkmcnt(0)" ::: "memory");
    __builtin_amdgcn_sched_barrier(0);
    __builtin_amdgcn_s_setprio(1);
#pragma unroll
    for (int mi = 0; mi < 4; ++mi)
#pragma unroll
      for (int ni = 0; ni < 4; ++ni) {
        acc[mi][ni] = __builtin_amdgcn_mfma_i32_16x16x64_i8(af[mi][0], bf[ni][0], acc[mi][ni], 0, 0, 0);
        acc[mi][ni] = __builtin_amdgcn_mfma_i32_16x16x64_i8(af[mi][1], bf[ni][1], acc[mi][ni], 0, 0, 0);
      }
    __builtin_amdgcn_s_setprio(0);
    if (stT) {
      stage(BSB(cur), gB, u + 2, 0);
      stage(BSB(cur), gB, u + 2, 1);
    }
#pragma unroll
    for (int mi = 0; mi < 4; ++mi) {
      ah[mi][0] = *reinterpret_cast<const i32x4*>(Ac + arowB + (4 + mi) * 2048 + colb0);
      ah[mi][1] = *reinterpret_cast<const i32x4*>(Ac + arowB + (4 + mi) * 2048 + colb1);
    }

    // ---- R2: [bar; lgkm0; MFMA hi] ; stage A(u+2); vmcnt; read u+1 frags ----
    __builtin_amdgcn_s_barrier();
    asm volatile("s_waitcnt lgkmcnt(0)" ::: "memory");
    __builtin_amdgcn_sched_barrier(0);
    __builtin_amdgcn_s_setprio(1);
#pragma unroll
    for (int mi = 0; mi < 4; ++mi)
#pragma unroll
      for (int ni = 0; ni < 4; ++ni) {
        acc[4 + mi][ni] = __builtin_amdgcn_mfma_i32_16x16x64_i8(ah[mi][0], bf[ni][0], acc[4 + mi][ni], 0, 0, 0);
        acc[4 + mi][ni] = __builtin_amdgcn_mfma_i32_16x16x64_i8(ah[mi][1], bf[ni][1], acc[4 + mi][ni], 0, 0, 0);
      }
    __builtin_amdgcn_s_setprio(0);
    if (stT) {
      stage(ASB(cur), gA, u + 2, 0);
      stage(ASB(cur), gA, u + 2, 1);
    }
    if (stT)
      asm volatile("s_waitcnt vmcnt(8)" ::: "memory");
    else
      asm volatile("s_waitcnt vmcnt(0)" ::: "memory");
    if (u + 1 < NKT) {
#pragma unroll
      for (int ni = 0; ni < 4; ++ni) {
        bf[ni][0] = *reinterpret_cast<const i32x4*>(Bn + browB + ni * 2048 + colb0);
        bf[ni][1] = *reinterpret_cast<const i32x4*>(Bn + browB + ni * 2048 + colb1);
      }
#pragma unroll
      for (int mi = 0; mi < 4; ++mi) {
        af[mi][0] = *reinterpret_cast<const i32x4*>(An + arowB + mi * 2048 + colb0);
        af[mi][1] = *reinterpret_cast<const i32x4*>(An + arowB + mi * 2048 + colb1);
      }
    }
  }

  // ---- epilogue: stage C through LDS (two 128-row passes) for contiguous stores ----
  float* cs = reinterpret_cast<float*>(SMEM); // [128][256] f32 = 128KB
  const int crow = (lane >> 4) * 4, ccol = lane & 15;
#pragma unroll
  for (int p = 0; p < 2; ++p) {
    __syncthreads();
    if (wr == p) {
#pragma unroll
      for (int mi = 0; mi < 8; ++mi) {
        const int rl = mi * 16 + crow;
        const int rowg = m0 + p * 128 + rl;
        float sxv[4];
#pragma unroll
        for (int r2 = 0; r2 < 4; ++r2) sxv[r2] = xs[rowg + r2];
#pragma unroll
        for (int ni = 0; ni < 4; ++ni) {
          const int col = wc * 64 + ni * 16 + ccol;
          const float sv = Scol[n0 + col];
          const float bv = bias[n0 + col];
#pragma unroll
          for (int r2 = 0; r2 < 4; ++r2)
            cs[(rl + r2) * 256 + col] =
                fmaf(sxv[r2] * sv, (float)acc[mi][ni][r2], bv);
        }
      }
    }
    __syncthreads();
    // store pass: wave wid owns rows wid*16 + rr; lane covers 4 f32 at lane*4.
    // Per wave per row: 64 lanes x 16B = 1024B contiguous NT store.
#pragma unroll
    for (int rr = 0; rr < 16; ++rr) {
      const int r = wid * 16 + rr;
      f32x4 v = *reinterpret_cast<const f32x4*>(cs + r * 256 + lane * 4);
      __builtin_nontemporal_store(
          v, reinterpret_cast<f32x4*>(out + (size_t)(m0 + p * 128 + r) * OUT_F + n0 + lane * 4));
    }
  }
}

// ---------------- fused fallback (ws too small): bf16 128^2 kernel ----------------
__global__ __launch_bounds__(256, 2) void gemm_fused(
    const float* __restrict__ x, const int* __restrict__ qw,
    const int* __restrict__ qz, const float* __restrict__ sc,
    const float* __restrict__ bias, float* __restrict__ out) {
  __shared__ u16 Asb[128 * 64];
  __shared__ u16 Bsb[128 * 64];
  const int tid = threadIdx.x;
  const int lane = tid & 63, wid = tid >> 6;
  const int bm = blockIdx.x & 31, bn = blockIdx.x >> 5;
  const int m0 = bm * 128, n0 = bn * 128;
  const int wr = wid >> 1, wc = wid & 1;
  const int frow = lane & 15, fk = (lane >> 4) * 8;
  f32x4 acc[4][4] = {};

  for (int kt = 0; kt < 64; ++kt) {
    const int k0 = kt * 64;
#pragma unroll
    for (int it = 0; it < 8; ++it) {
      int c = it * 256 + tid;
      int row = c >> 4, c4 = c & 15;
      float4 v = *reinterpret_cast<const float4*>(
          x + (size_t)(m0 + row) * IN_F + k0 + c4 * 4);
      uint2 o;
      o.x = (u32)f2bf(v.x) | ((u32)f2bf(v.y) << 16);
      o.y = (u32)f2bf(v.z) | ((u32)f2bf(v.w) << 16);
      *reinterpret_cast<uint2*>(Asb + row * 64 + c4 * 4) = o;
    }
    {
      int nl = tid & 127, rq = tid >> 7;
      int n = n0 + nl;
      int gq = k0 >> 7;
      int z = (int)(((u32)qz[gq * QZ_STRIDE + (n >> 3)] >> (4 * (n & 7))) & 15u);
      float s = sc[gq * OUT_F + n];
#pragma unroll
      for (int j = 0; j < 4; ++j) {
        int r = (k0 >> 3) + rq * 4 + j;
        u32 q = (u32)qw[(size_t)r * OUT_F + n];
        u32 o[4];
#pragma unroll
        for (int e = 0; e < 4; ++e) {
          u16 lo = f2bf(s * (float)((int)((q >> (8 * e)) & 15u) - z));
          u16 hi = f2bf(s * (float)((int)((q >> (8 * e + 4)) & 15u) - z));
          o[e] = (u32)lo | ((u32)hi << 16);
        }
        *reinterpret_cast<uint4*>(Bsb + nl * 64 + (rq * 4 + j) * 8) =
            make_uint4(o[0], o[1], o[2], o[3]);
      }
    }
    __syncthreads();
#pragma unroll
    for (int kk = 0; kk < 64; kk += 32) {
      bf16x8 a[4], b[4];
#pragma unroll
      for (int mi = 0; mi < 4; ++mi)
        a[mi] = *reinterpret_cast<const bf16x8*>(Asb + (wr * 64 + mi * 16 + frow) * 64 + kk + fk);
#pragma unroll
      for (int ni = 0; ni < 4; ++ni)
        b[ni] = *reinterpret_cast<const bf16x8*>(Bsb + (wc * 64 + ni * 16 + frow) * 64 + kk + fk);
#pragma unroll
      for (int mi = 0; mi < 4; ++mi)
#pragma unroll
        for (int ni = 0; ni < 4; ++ni)
          acc[mi][ni] = __builtin_amdgcn_mfma_f32_16x16x32_bf16(a[mi], b[ni], acc[mi][ni], 0, 0, 0);
    }
    __syncthreads();
  }
  const int crow = (lane >> 4) * 4, ccol = lane & 15;
#pragma unroll
  for (int mi = 0; mi < 4; ++mi) {
#pragma unroll
    for (int ni = 0; ni < 4; ++ni) {
      int col = n0 + wc * 64 + ni * 16 + ccol;
      float bv = bias[col];
      int rowb = m0 + wr * 64 + mi * 16 + crow;
#pragma unroll
      for (int r2 = 0; r2 < 4; ++r2)
        out[(size_t)(rowb + r2) * OUT_F + col] = acc[mi][ni][r2] + bv;
    }
  }
}

extern "C" void kernel_launch(void* const* d_in, const int* in_sizes, int n_in,
                              void* d_out, int out_size, void* d_ws, size_t ws_size,
                              hipStream_t stream) {
  const float* x = (const float*)d_in[0];
  const int* qw = (const int*)d_in[1];
  const float* sc = (const float*)d_in[2];
  const int* qz = (const int*)d_in[3];
  const float* bias = (const float*)d_in[4];
  float* out = (float*)d_out;

  const size_t xq_bytes = (size_t)M_ROWS * IN_F;  // 16 MiB
  const size_t wq_bytes = (size_t)OUT_F * IN_F;   // ~43 MiB
  const size_t xs_bytes = (size_t)M_ROWS * 4;     // 16 KiB
  const size_t sc_bytes = (size_t)OUT_F * 4;      // 43 KiB each

  if (ws_size >= xq_bytes + wq_bytes + xs_bytes + 2 * sc_bytes) {
    u8* xqp = (u8*)d_ws;
    u8* wqp = (u8*)d_ws + xq_bytes;
    float* xsp = (float*)((u8*)d_ws + xq_bytes + wq_bytes);
    float* Scolp = (float*)((u8*)d_ws + xq_bytes + wq_bytes + xs_bytes);
    float* invScolp = Scolp + OUT_F;
    hipLaunchKernelGGL(conv_x_i8, dim3(M_ROWS), dim3(256), 0, stream, x, xqp, xsp);
    hipLaunchKernelGGL(colscale_kernel, dim3((OUT_F + 255) / 256), dim3(256), 0,
                       stream, sc, Scolp, invScolp);
    hipLaunchKernelGGL(dequant_i8, dim3(OUT_F / 32, 512 / 8), dim3(256), 0,
                       stream, qw, qz, sc, invScolp, wqp);
    hipLaunchKernelGGL(gemm256_i8, dim3((M_ROWS / 256) * (OUT_F / 256)),
                       dim3(512), 0, stream, xqp, wqp, Scolp, xsp, bias, out);
  } else {
    hipLaunchKernelGGL(gemm_fused, dim3(32 * 86), dim3(256), 0, stream, x, qw,
                       qz, sc, bias, out);
  }
}